// Round 1
// 615.258 us; speedup vs baseline: 1.0158x; 1.0158x over previous
//
#include <hip/hip_runtime.h>
#include <stdint.h>

#define TT 128
#define BSZ 512
#define HID 512
#define KDIM 512
#define BH (BSZ*HID)   // 262144 neurons

// ---------------- fp32 tiled GEMM: C[m][n] = sum_k A[m][k] * W[n][k] + bias[n] --------
// v2: 128x256 block tile, 256 threads, 8x16 microtile, BK=16, DOUBLE-BUFFERED LDS (one
// barrier per k-tile), LDS transposed [k][m]/[k][n] with +4 pad (132/260; both == 4 mod 32
// -> same proven conflict-free bank pattern: 2-way max, free).
// WHY 8x16: v1 (8x8) was LDS-throughput-bound: per wave-tile LDS ~861 CU-cyc (64 b128
// reads @~12cyc + 16 b32 writes) vs 512 CU-cyc-equiv of fma -> 1.68x oversubscribed
// (matches 415us vs 218us fp32 roofline). 8x16 halves LDS bytes/fma (1.0 -> 0.75
// B/lane-fma): 96 b128 reads per 2048 fma -> ~1.26x -> predicted ~270-300us.
// VGPR ~200 (128 acc + frags + prefetch) -> 2 waves/SIMD, 2 blocks/CU (LDS 50176 B).
// NUMERICS CONTRACT (bit-exact vs np ref, absmax 0.0): per output element the
// reduction is ONE sequential fma chain over k ascending, fp32. Do not reorder/split.
__global__ __launch_bounds__(256, 2) void gemm_f32(
    const float* __restrict__ A, const float* __restrict__ W,
    const float* __restrict__ bias, float* __restrict__ C) {
  __shared__ float As[2][16][132];   // [buf][k][m], +4/row bank shift
  __shared__ float Bs[2][16][260];   // [buf][k][n], +4/row bank shift
  const int t  = threadIdx.x;
  const int m0 = blockIdx.y * 128;
  const int n0 = blockIdx.x * 256;
  const int tx = t & 15;          // n group: cols {tx*4..+3} in each 64-wide quarter
  const int ty = t >> 4;          // m group: rows ty*8..ty*8+7
  const int r0 = t >> 2;          // staging row 0..63 (+64/+128/+192 replicas)
  const int kg = t & 3;           // k float4 group within 16-wide k tile

  float acc[8][16];
  #pragma unroll
  for (int i = 0; i < 8; ++i)
    #pragma unroll
    for (int j = 0; j < 16; ++j) acc[i][j] = 0.f;

  const float* Ap = A + (size_t)(m0 + r0) * KDIM + kg * 4;
  const float* Wp = W + (size_t)(n0 + r0) * KDIM + kg * 4;

  float4 a0 = *(const float4*)Ap;
  float4 a1 = *(const float4*)(Ap + (size_t)64  * KDIM);
  float4 w0 = *(const float4*)Wp;
  float4 w1 = *(const float4*)(Wp + (size_t)64  * KDIM);
  float4 w2 = *(const float4*)(Wp + (size_t)128 * KDIM);
  float4 w3 = *(const float4*)(Wp + (size_t)192 * KDIM);

  // stage tile into buffer BUF (24 b32 scatter writes; 2-way bank alias only -> free)
  #define STAGE(BUF) do { \
    As[BUF][kg*4+0][r0]     = a0.x; As[BUF][kg*4+1][r0]     = a0.y; \
    As[BUF][kg*4+2][r0]     = a0.z; As[BUF][kg*4+3][r0]     = a0.w; \
    As[BUF][kg*4+0][r0+64]  = a1.x; As[BUF][kg*4+1][r0+64]  = a1.y; \
    As[BUF][kg*4+2][r0+64]  = a1.z; As[BUF][kg*4+3][r0+64]  = a1.w; \
    Bs[BUF][kg*4+0][r0]     = w0.x; Bs[BUF][kg*4+1][r0]     = w0.y; \
    Bs[BUF][kg*4+2][r0]     = w0.z; Bs[BUF][kg*4+3][r0]     = w0.w; \
    Bs[BUF][kg*4+0][r0+64]  = w1.x; Bs[BUF][kg*4+1][r0+64]  = w1.y; \
    Bs[BUF][kg*4+2][r0+64]  = w1.z; Bs[BUF][kg*4+3][r0+64]  = w1.w; \
    Bs[BUF][kg*4+0][r0+128] = w2.x; Bs[BUF][kg*4+1][r0+128] = w2.y; \
    Bs[BUF][kg*4+2][r0+128] = w2.z; Bs[BUF][kg*4+3][r0+128] = w2.w; \
    Bs[BUF][kg*4+0][r0+192] = w3.x; Bs[BUF][kg*4+1][r0+192] = w3.y; \
    Bs[BUF][kg*4+2][r0+192] = w3.z; Bs[BUF][kg*4+3][r0+192] = w3.w; \
  } while (0)

  STAGE(0);

  int cur = 0;
  for (int k0 = 0; k0 < KDIM; k0 += 16) {
    // Single barrier per tile. Drains lgkmcnt -> (a) buf[cur] writes visible,
    // (b) previous iteration's ds_reads of buf[cur^1] complete, so staging into
    // buf[cur^1] below is safe.
    __syncthreads();
    const bool more = (k0 + 16 < KDIM);
    if (more) {   // global prefetch of next tile; latency hidden under the fma block
      a0 = *(const float4*)(Ap + k0 + 16);
      a1 = *(const float4*)(Ap + (size_t)64  * KDIM + k0 + 16);
      w0 = *(const float4*)(Wp + k0 + 16);
      w1 = *(const float4*)(Wp + (size_t)64  * KDIM + k0 + 16);
      w2 = *(const float4*)(Wp + (size_t)128 * KDIM + k0 + 16);
      w3 = *(const float4*)(Wp + (size_t)192 * KDIM + k0 + 16);
    }

    #pragma unroll
    for (int kk = 0; kk < 16; ++kk) {
      const float4 xa0 = *(const float4*)&As[cur][kk][ty*8];        // broadcast x16 lanes
      const float4 xa1 = *(const float4*)&As[cur][kk][ty*8 + 4];
      const float4 xb0 = *(const float4*)&Bs[cur][kk][tx*4];        // 2-way alias: free
      const float4 xb1 = *(const float4*)&Bs[cur][kk][64  + tx*4];
      const float4 xb2 = *(const float4*)&Bs[cur][kk][128 + tx*4];
      const float4 xb3 = *(const float4*)&Bs[cur][kk][192 + tx*4];
      const float a[8]  = {xa0.x,xa0.y,xa0.z,xa0.w,xa1.x,xa1.y,xa1.z,xa1.w};
      const float b[16] = {xb0.x,xb0.y,xb0.z,xb0.w, xb1.x,xb1.y,xb1.z,xb1.w,
                           xb2.x,xb2.y,xb2.z,xb2.w, xb3.x,xb3.y,xb3.z,xb3.w};
      #pragma unroll
      for (int i = 0; i < 8; ++i)
        #pragma unroll
        for (int j = 0; j < 16; ++j)
          acc[i][j] = __builtin_fmaf(a[i], b[j], acc[i][j]);
    }

    if (more) {
      const int nb = cur ^ 1;
      STAGE(nb);      // overlaps other block's compute; protected by next barrier
    }
    cur ^= 1;
  }
  #undef STAGE

  // epilogue: + bias (ref adds b once to xp — identical), coalesced float4 stores
  float4 bv[4];
  #pragma unroll
  for (int q = 0; q < 4; ++q) bv[q] = *(const float4*)&bias[n0 + 64*q + tx*4];
  #pragma unroll
  for (int i = 0; i < 8; ++i) {
    float* cp = C + (size_t)(m0 + ty*8 + i) * HID + n0 + tx*4;
    #pragma unroll
    for (int q = 0; q < 4; ++q) {
      const float4 v = {acc[i][q*4+0] + bv[q].x, acc[i][q*4+1] + bv[q].y,
                        acc[i][q*4+2] + bv[q].z, acc[i][q*4+3] + bv[q].w};
      *(float4*)(cp + 64*q) = v;
    }
  }
}

// ---------------- LIF scan (bit-identical to np fp32 reference given xp) ----------------
__device__ __forceinline__ float lif_step(float y, float v[4], float av[4]) {
  float as3 = 0.f;
  #pragma unroll
  for (int l = 0; l < 4; ++l) {
    float vv = v[l];
    float accv = 0.f, accs = 0.f;
    #pragma unroll
    for (int k = 0; k < 4; ++k) {
      const float d = y - vv;                        // round(inp - v)
      vv = __builtin_fmaf(d, 0.5f, vv);              // round(v + d*0.5): d*0.5 exact
      const float spk = (vv >= 1.0f) ? 1.0f : 0.0f;  // v-1>=0 <=> v>=1 (exact)
      vv -= spk;                                     // soft reset
      accv += vv;
      accs += spk;
    }
    v[l] = vv;
    const float a = accv * 0.25f;                    // exact /4
    av[l] = a;
    y = a;                                           // next layer consumes avg_v
    as3 = accs;
  }
  return as3;
}

// One thread per neuron. xp loads are INDEPENDENT across t (precomputed array), so we
// run a 4-deep prefetch: 4 loads in flight cover ~900-cycle HBM latency with ~960
// issue-cycles of LIF compute per group.
__global__ __launch_bounds__(256) void lif_scan(
    const float* __restrict__ xp, float* __restrict__ outp, float* __restrict__ vstate,
    int tc, int first, int last) {
  const int idx = blockIdx.x * 256 + threadIdx.x;
  float v[4];
  if (first) {
    #pragma unroll
    for (int l = 0; l < 4; ++l) v[l] = 0.f;
  } else {
    #pragma unroll
    for (int l = 0; l < 4; ++l) v[l] = vstate[(size_t)l * BH + idx];
  }
  float av[4] = {0.f, 0.f, 0.f, 0.f};
  const float* p = xp + idx;
  float* op = outp + idx;

  if ((tc & 3) == 0 && tc >= 8) {
    float curb[4];
    #pragma unroll
    for (int i = 0; i < 4; ++i) curb[i] = p[(size_t)i * BH];
    for (int t = 0; t + 4 < tc; t += 4) {
      float nxtb[4];
      #pragma unroll
      for (int i = 0; i < 4; ++i) nxtb[i] = p[(size_t)(i + 4) * BH];  // issued pre-compute
      #pragma unroll
      for (int i = 0; i < 4; ++i) {
        const float as3 = lif_step(curb[i], v, av);
        op[(size_t)i * BH] = as3 * 0.25f;
      }
      #pragma unroll
      for (int i = 0; i < 4; ++i) curb[i] = nxtb[i];
      p += 4 * BH; op += 4 * BH;
    }
    #pragma unroll
    for (int i = 0; i < 4; ++i) {    // tail group, already in registers
      const float as3 = lif_step(curb[i], v, av);
      op[(size_t)i * BH] = as3 * 0.25f;
    }
  } else {
    for (int t = 0; t < tc; ++t) {
      const float as3 = lif_step(p[0], v, av);
      *op = as3 * 0.25f;
      p += BH; op += BH;
    }
  }

  if (last) {
    #pragma unroll
    for (int l = 0; l < 4; ++l) vstate[(size_t)l * BH + idx] = av[l];
  } else {
    #pragma unroll
    for (int l = 0; l < 4; ++l) vstate[(size_t)l * BH + idx] = v[l];
  }
}

extern "C" void kernel_launch(void* const* d_in, const int* in_sizes, int n_in,
                              void* d_out, int out_size, void* d_ws, size_t ws_size,
                              hipStream_t stream) {
  const float* x = (const float*)d_in[0];   // [128,512,512] fp32
  const float* W = (const float*)d_in[1];   // [512,512] fp32
  const float* b = (const float*)d_in[2];   // [512] fp32
  float* out    = (float*)d_out;            // [128,512,512] avg spikes (fp32)
  float* states = out + (size_t)TT * BH;    // [4,512,512] final avg_v; also chunk-carry v

  int tc = TT;                              // xp chunk: tc MiB of ws
  while (tc > 1 && (size_t)tc * BH * 4ull > ws_size) tc >>= 1;
  float* xp = (float*)d_ws;
  const int nc = TT / tc;

  for (int c = 0; c < nc; ++c) {
    hipLaunchKernelGGL(gemm_f32, dim3(HID / 256, tc * BSZ / 128), dim3(256), 0, stream,
                       x + (size_t)c * tc * BH, W, b, xp);
    hipLaunchKernelGGL(lif_scan, dim3(BH / 256), dim3(256), 0, stream,
                       xp, out + (size_t)c * tc * BH, states,
                       tc, c == 0 ? 1 : 0, c == nc - 1 ? 1 : 0);
  }
}

// Round 2
// 608.492 us; speedup vs baseline: 1.0271x; 1.0111x over previous
//
#include <hip/hip_runtime.h>
#include <stdint.h>

#define TT 128
#define BSZ 512
#define HID 512
#define KDIM 512
#define BH (BSZ*HID)   // 262144 neurons

// ---------------- fp32 tiled GEMM: C[m][n] = sum_k A[m][k] * W[n][k] + bias[n] --------
// v3: 128x256 block tile, 256 threads, 8x16 microtile, BK=16, double-buffered LDS,
// one barrier per k-tile. LDS transposed [k][m]/[k][n], +4 pad (both 132/260 == 4 mod 32,
// conflict-free: 2-way max = free).
// v2 -> v3: __launch_bounds__(256,2) made the compiler clamp to 128 arch VGPRs (its
// 4-wave/SIMD occupancy boundary) and park ~50 live values in AGPRs; the resulting
// v_accvgpr_read/write shuffle was ~+37% VALU instructions (VALUBusy 73.6% x 403us =
// 297us vs 218us pure-fma issue). Fix: (256,1) -> cap 512, expect ~180-200 VGPRs,
// 2 waves/SIMD (LDS 50176B already limits blocks/CU). Inner fma block consumes B one
// float4-quarter at a time so peak live regs ~= 128 acc + 8 a + 4 b + 24 prefetch + addr.
// LDS-pipe floor for this shape ~250-260us (12.9GB ds_read @ ~52TB/s sustained b128).
// NUMERICS CONTRACT (bit-exact vs np ref, absmax 0.0): per output element the
// reduction is ONE sequential fma chain over k ascending, fp32. Do not reorder/split.
__global__ __launch_bounds__(256, 1) void gemm_f32(
    const float* __restrict__ A, const float* __restrict__ W,
    const float* __restrict__ bias, float* __restrict__ C) {
  __shared__ float As[2][16][132];   // [buf][k][m], +4/row bank shift
  __shared__ float Bs[2][16][260];   // [buf][k][n], +4/row bank shift
  const int t  = threadIdx.x;
  const int m0 = blockIdx.y * 128;
  const int n0 = blockIdx.x * 256;
  const int tx = t & 15;          // n group: cols {tx*4..+3} in each 64-wide quarter
  const int ty = t >> 4;          // m group: rows ty*8..ty*8+7
  const int r0 = t >> 2;          // staging row 0..63 (+64/+128/+192 replicas)
  const int kg = t & 3;           // k float4 group within 16-wide k tile

  float acc[8][16];
  #pragma unroll
  for (int i = 0; i < 8; ++i)
    #pragma unroll
    for (int j = 0; j < 16; ++j) acc[i][j] = 0.f;

  const float* Ap = A + (size_t)(m0 + r0) * KDIM + kg * 4;
  const float* Wp = W + (size_t)(n0 + r0) * KDIM + kg * 4;

  float4 a0 = *(const float4*)Ap;
  float4 a1 = *(const float4*)(Ap + (size_t)64  * KDIM);
  float4 w0 = *(const float4*)Wp;
  float4 w1 = *(const float4*)(Wp + (size_t)64  * KDIM);
  float4 w2 = *(const float4*)(Wp + (size_t)128 * KDIM);
  float4 w3 = *(const float4*)(Wp + (size_t)192 * KDIM);

  // stage tile into buffer BUF (24 b32 scatter writes; 2-way bank alias only -> free)
  #define STAGE(BUF) do { \
    As[BUF][kg*4+0][r0]     = a0.x; As[BUF][kg*4+1][r0]     = a0.y; \
    As[BUF][kg*4+2][r0]     = a0.z; As[BUF][kg*4+3][r0]     = a0.w; \
    As[BUF][kg*4+0][r0+64]  = a1.x; As[BUF][kg*4+1][r0+64]  = a1.y; \
    As[BUF][kg*4+2][r0+64]  = a1.z; As[BUF][kg*4+3][r0+64]  = a1.w; \
    Bs[BUF][kg*4+0][r0]     = w0.x; Bs[BUF][kg*4+1][r0]     = w0.y; \
    Bs[BUF][kg*4+2][r0]     = w0.z; Bs[BUF][kg*4+3][r0]     = w0.w; \
    Bs[BUF][kg*4+0][r0+64]  = w1.x; Bs[BUF][kg*4+1][r0+64]  = w1.y; \
    Bs[BUF][kg*4+2][r0+64]  = w1.z; Bs[BUF][kg*4+3][r0+64]  = w1.w; \
    Bs[BUF][kg*4+0][r0+128] = w2.x; Bs[BUF][kg*4+1][r0+128] = w2.y; \
    Bs[BUF][kg*4+2][r0+128] = w2.z; Bs[BUF][kg*4+3][r0+128] = w2.w; \
    Bs[BUF][kg*4+0][r0+192] = w3.x; Bs[BUF][kg*4+1][r0+192] = w3.y; \
    Bs[BUF][kg*4+2][r0+192] = w3.z; Bs[BUF][kg*4+3][r0+192] = w3.w; \
  } while (0)

  STAGE(0);

  int cur = 0;
  for (int k0 = 0; k0 < KDIM; k0 += 16) {
    // Single barrier per tile. Drains lgkmcnt -> (a) buf[cur] writes visible,
    // (b) previous iteration's ds_reads of buf[cur^1] complete, so staging into
    // buf[cur^1] below is safe.
    __syncthreads();
    const bool more = (k0 + 16 < KDIM);
    if (more) {   // global prefetch of next tile; latency hidden under the fma block
      a0 = *(const float4*)(Ap + k0 + 16);
      a1 = *(const float4*)(Ap + (size_t)64  * KDIM + k0 + 16);
      w0 = *(const float4*)(Wp + k0 + 16);
      w1 = *(const float4*)(Wp + (size_t)64  * KDIM + k0 + 16);
      w2 = *(const float4*)(Wp + (size_t)128 * KDIM + k0 + 16);
      w3 = *(const float4*)(Wp + (size_t)192 * KDIM + k0 + 16);
    }

    #pragma unroll
    for (int kk = 0; kk < 16; ++kk) {
      const float4 xa0 = *(const float4*)&As[cur][kk][ty*8];        // broadcast x16 lanes
      const float4 xa1 = *(const float4*)&As[cur][kk][ty*8 + 4];
      const float a[8] = {xa0.x,xa0.y,xa0.z,xa0.w,xa1.x,xa1.y,xa1.z,xa1.w};
      // One B-quarter (4 regs) live at a time: peak pressure fits arch VGPRs, no AGPR
      // round-trips. Per-acc-element k-order unchanged.
      #pragma unroll
      for (int q = 0; q < 4; ++q) {
        const float4 xb = *(const float4*)&Bs[cur][kk][64*q + tx*4]; // 2-way alias: free
        #pragma unroll
        for (int i = 0; i < 8; ++i) {
          acc[i][q*4+0] = __builtin_fmaf(a[i], xb.x, acc[i][q*4+0]);
          acc[i][q*4+1] = __builtin_fmaf(a[i], xb.y, acc[i][q*4+1]);
          acc[i][q*4+2] = __builtin_fmaf(a[i], xb.z, acc[i][q*4+2]);
          acc[i][q*4+3] = __builtin_fmaf(a[i], xb.w, acc[i][q*4+3]);
        }
      }
    }

    if (more) {
      const int nb = cur ^ 1;
      STAGE(nb);      // overlaps other waves' compute; protected by next barrier
    }
    cur ^= 1;
  }
  #undef STAGE

  // epilogue: + bias (ref adds b once to xp — identical), coalesced float4 stores
  float4 bv[4];
  #pragma unroll
  for (int q = 0; q < 4; ++q) bv[q] = *(const float4*)&bias[n0 + 64*q + tx*4];
  #pragma unroll
  for (int i = 0; i < 8; ++i) {
    float* cp = C + (size_t)(m0 + ty*8 + i) * HID + n0 + tx*4;
    #pragma unroll
    for (int q = 0; q < 4; ++q) {
      const float4 v = {acc[i][q*4+0] + bv[q].x, acc[i][q*4+1] + bv[q].y,
                        acc[i][q*4+2] + bv[q].z, acc[i][q*4+3] + bv[q].w};
      *(float4*)(cp + 64*q) = v;
    }
  }
}

// ---------------- LIF scan (bit-identical to np fp32 reference given xp) ----------------
__device__ __forceinline__ float lif_step(float y, float v[4], float av[4]) {
  float as3 = 0.f;
  #pragma unroll
  for (int l = 0; l < 4; ++l) {
    float vv = v[l];
    float accv = 0.f, accs = 0.f;
    #pragma unroll
    for (int k = 0; k < 4; ++k) {
      const float d = y - vv;                        // round(inp - v)
      vv = __builtin_fmaf(d, 0.5f, vv);              // round(v + d*0.5): d*0.5 exact
      const float spk = (vv >= 1.0f) ? 1.0f : 0.0f;  // v-1>=0 <=> v>=1 (exact)
      vv -= spk;                                     // soft reset
      accv += vv;
      accs += spk;
    }
    v[l] = vv;
    const float a = accv * 0.25f;                    // exact /4
    av[l] = a;
    y = a;                                           // next layer consumes avg_v
    as3 = accs;
  }
  return as3;
}

// One thread per neuron. xp loads are INDEPENDENT across t (precomputed array), so we
// run a 4-deep prefetch: 4 loads in flight cover ~900-cycle HBM latency with ~960
// issue-cycles of LIF compute per group.
__global__ __launch_bounds__(256) void lif_scan(
    const float* __restrict__ xp, float* __restrict__ outp, float* __restrict__ vstate,
    int tc, int first, int last) {
  const int idx = blockIdx.x * 256 + threadIdx.x;
  float v[4];
  if (first) {
    #pragma unroll
    for (int l = 0; l < 4; ++l) v[l] = 0.f;
  } else {
    #pragma unroll
    for (int l = 0; l < 4; ++l) v[l] = vstate[(size_t)l * BH + idx];
  }
  float av[4] = {0.f, 0.f, 0.f, 0.f};
  const float* p = xp + idx;
  float* op = outp + idx;

  if ((tc & 3) == 0 && tc >= 8) {
    float curb[4];
    #pragma unroll
    for (int i = 0; i < 4; ++i) curb[i] = p[(size_t)i * BH];
    for (int t = 0; t + 4 < tc; t += 4) {
      float nxtb[4];
      #pragma unroll
      for (int i = 0; i < 4; ++i) nxtb[i] = p[(size_t)(i + 4) * BH];  // issued pre-compute
      #pragma unroll
      for (int i = 0; i < 4; ++i) {
        const float as3 = lif_step(curb[i], v, av);
        op[(size_t)i * BH] = as3 * 0.25f;
      }
      #pragma unroll
      for (int i = 0; i < 4; ++i) curb[i] = nxtb[i];
      p += 4 * BH; op += 4 * BH;
    }
    #pragma unroll
    for (int i = 0; i < 4; ++i) {    // tail group, already in registers
      const float as3 = lif_step(curb[i], v, av);
      op[(size_t)i * BH] = as3 * 0.25f;
    }
  } else {
    for (int t = 0; t < tc; ++t) {
      const float as3 = lif_step(p[0], v, av);
      *op = as3 * 0.25f;
      p += BH; op += BH;
    }
  }

  if (last) {
    #pragma unroll
    for (int l = 0; l < 4; ++l) vstate[(size_t)l * BH + idx] = av[l];
  } else {
    #pragma unroll
    for (int l = 0; l < 4; ++l) vstate[(size_t)l * BH + idx] = v[l];
  }
}

extern "C" void kernel_launch(void* const* d_in, const int* in_sizes, int n_in,
                              void* d_out, int out_size, void* d_ws, size_t ws_size,
                              hipStream_t stream) {
  const float* x = (const float*)d_in[0];   // [128,512,512] fp32
  const float* W = (const float*)d_in[1];   // [512,512] fp32
  const float* b = (const float*)d_in[2];   // [512] fp32
  float* out    = (float*)d_out;            // [128,512,512] avg spikes (fp32)
  float* states = out + (size_t)TT * BH;    // [4,512,512] final avg_v; also chunk-carry v

  int tc = TT;                              // xp chunk: tc MiB of ws
  while (tc > 1 && (size_t)tc * BH * 4ull > ws_size) tc >>= 1;
  float* xp = (float*)d_ws;
  const int nc = TT / tc;

  for (int c = 0; c < nc; ++c) {
    hipLaunchKernelGGL(gemm_f32, dim3(HID / 256, tc * BSZ / 128), dim3(256), 0, stream,
                       x + (size_t)c * tc * BH, W, b, xp);
    hipLaunchKernelGGL(lif_scan, dim3(BH / 256), dim3(256), 0, stream,
                       xp, out + (size_t)c * tc * BH, states,
                       tc, c == 0 ? 1 : 0, c == nc - 1 ? 1 : 0);
  }
}

// Round 3
// 594.836 us; speedup vs baseline: 1.0507x; 1.0230x over previous
//
#include <hip/hip_runtime.h>
#include <stdint.h>

#define TT 128
#define BSZ 512
#define HID 512
#define KDIM 512
#define BH (BSZ*HID)   // 262144 neurons

typedef float v2f __attribute__((ext_vector_type(2)));

// ---------------- fp32 tiled GEMM: C[m][n] = sum_k A[m][k] * W[n][k] + bias[n] --------
// v4: 128x256 block tile, 256 threads, 8x16 microtile, BK=16, double-buffered LDS,
// one barrier per k-tile. LDS transposed [k][m]/[k][n], +4 pad (conflict-free).
// v3 -> v4: v1/v2/v3 all converged on the same invariant: VALU busy-time ~282-297us
// (vs 218us pure-fma issue) + ~120us VALU-idle; compiler pins 128 arch VGPRs + AGPR
// parking regardless of launch bounds. New lever: PACKED fp32 — v_pk_fma_f32 does two
// independent IEEE fp32 FMAs per lane per instruction (CDNA2: 2x advertised; CDNA3's
// 163.4TF headline IS the packed rate). Emitted via __builtin_elementwise_fma on float2
// (guaranteed fma; clang selects v_pk_fma_f32 on gfx90a+). Packing is across j (two
// adjacent acc columns); each acc element's k-ascending fp32 fma chain is UNTOUCHED.
// NUMERICS CONTRACT (bit-exact vs np ref, absmax 0.0): per output element the
// reduction is ONE sequential fp32 fma chain over k ascending. Do not reorder/split.
__global__ __launch_bounds__(256, 1) void gemm_f32(
    const float* __restrict__ A, const float* __restrict__ W,
    const float* __restrict__ bias, float* __restrict__ C) {
  __shared__ float As[2][16][132];   // [buf][k][m], +4/row bank shift
  __shared__ float Bs[2][16][260];   // [buf][k][n], +4/row bank shift
  const int t  = threadIdx.x;
  const int m0 = blockIdx.y * 128;
  const int n0 = blockIdx.x * 256;
  const int tx = t & 15;          // n group: cols {tx*4..+3} in each 64-wide quarter
  const int ty = t >> 4;          // m group: rows ty*8..ty*8+7
  const int r0 = t >> 2;          // staging row 0..63 (+64/+128/+192 replicas)
  const int kg = t & 3;           // k float4 group within 16-wide k tile

  v2f acc[8][8];                  // [i][jpair]: acc[i][p] = {C(i,2p), C(i,2p+1)}
  #pragma unroll
  for (int i = 0; i < 8; ++i)
    #pragma unroll
    for (int j = 0; j < 8; ++j) acc[i][j] = (v2f){0.f, 0.f};

  const float* Ap = A + (size_t)(m0 + r0) * KDIM + kg * 4;
  const float* Wp = W + (size_t)(n0 + r0) * KDIM + kg * 4;

  float4 a0 = *(const float4*)Ap;
  float4 a1 = *(const float4*)(Ap + (size_t)64  * KDIM);
  float4 w0 = *(const float4*)Wp;
  float4 w1 = *(const float4*)(Wp + (size_t)64  * KDIM);
  float4 w2 = *(const float4*)(Wp + (size_t)128 * KDIM);
  float4 w3 = *(const float4*)(Wp + (size_t)192 * KDIM);

  // stage tile into buffer BUF (24 b32 scatter writes; 2-way bank alias only -> free)
  #define STAGE(BUF) do { \
    As[BUF][kg*4+0][r0]     = a0.x; As[BUF][kg*4+1][r0]     = a0.y; \
    As[BUF][kg*4+2][r0]     = a0.z; As[BUF][kg*4+3][r0]     = a0.w; \
    As[BUF][kg*4+0][r0+64]  = a1.x; As[BUF][kg*4+1][r0+64]  = a1.y; \
    As[BUF][kg*4+2][r0+64]  = a1.z; As[BUF][kg*4+3][r0+64]  = a1.w; \
    Bs[BUF][kg*4+0][r0]     = w0.x; Bs[BUF][kg*4+1][r0]     = w0.y; \
    Bs[BUF][kg*4+2][r0]     = w0.z; Bs[BUF][kg*4+3][r0]     = w0.w; \
    Bs[BUF][kg*4+0][r0+64]  = w1.x; Bs[BUF][kg*4+1][r0+64]  = w1.y; \
    Bs[BUF][kg*4+2][r0+64]  = w1.z; Bs[BUF][kg*4+3][r0+64]  = w1.w; \
    Bs[BUF][kg*4+0][r0+128] = w2.x; Bs[BUF][kg*4+1][r0+128] = w2.y; \
    Bs[BUF][kg*4+2][r0+128] = w2.z; Bs[BUF][kg*4+3][r0+128] = w2.w; \
    Bs[BUF][kg*4+0][r0+192] = w3.x; Bs[BUF][kg*4+1][r0+192] = w3.y; \
    Bs[BUF][kg*4+2][r0+192] = w3.z; Bs[BUF][kg*4+3][r0+192] = w3.w; \
  } while (0)

  STAGE(0);

  int cur = 0;
  for (int k0 = 0; k0 < KDIM; k0 += 16) {
    // Single barrier per tile. Drains lgkmcnt -> (a) buf[cur] writes visible,
    // (b) previous iteration's ds_reads of buf[cur^1] complete, so staging into
    // buf[cur^1] below is safe.
    __syncthreads();
    const bool more = (k0 + 16 < KDIM);
    if (more) {   // global prefetch of next tile; latency hidden under the fma block
      a0 = *(const float4*)(Ap + k0 + 16);
      a1 = *(const float4*)(Ap + (size_t)64  * KDIM + k0 + 16);
      w0 = *(const float4*)(Wp + k0 + 16);
      w1 = *(const float4*)(Wp + (size_t)64  * KDIM + k0 + 16);
      w2 = *(const float4*)(Wp + (size_t)128 * KDIM + k0 + 16);
      w3 = *(const float4*)(Wp + (size_t)192 * KDIM + k0 + 16);
    }

    #pragma unroll
    for (int kk = 0; kk < 16; ++kk) {
      const float4 xa0 = *(const float4*)&As[cur][kk][ty*8];        // broadcast x16 lanes
      const float4 xa1 = *(const float4*)&As[cur][kk][ty*8 + 4];
      const float a[8] = {xa0.x,xa0.y,xa0.z,xa0.w,xa1.x,xa1.y,xa1.z,xa1.w};
      v2f ad[8];                                   // lane-pair broadcast of a[i]
      #pragma unroll
      for (int i = 0; i < 8; ++i) ad[i] = (v2f){a[i], a[i]};
      // One B-quarter (4 floats = 2 pairs) live at a time; 64 v_pk_fma per kk replaces
      // 128 v_fma. Per-acc-element k-order unchanged (pack is across j only).
      #pragma unroll
      for (int q = 0; q < 4; ++q) {
        const float4 xb = *(const float4*)&Bs[cur][kk][64*q + tx*4]; // 2-way alias: free
        const v2f b0 = (v2f){xb.x, xb.y};
        const v2f b1 = (v2f){xb.z, xb.w};
        #pragma unroll
        for (int i = 0; i < 8; ++i) {
          acc[i][2*q]   = __builtin_elementwise_fma(ad[i], b0, acc[i][2*q]);
          acc[i][2*q+1] = __builtin_elementwise_fma(ad[i], b1, acc[i][2*q+1]);
        }
      }
    }

    if (more) {
      const int nb = cur ^ 1;
      STAGE(nb);      // overlaps other waves' compute; protected by next barrier
    }
    cur ^= 1;
  }
  #undef STAGE

  // epilogue: + bias (ref adds b once to xp — identical), coalesced float4 stores
  float4 bv[4];
  #pragma unroll
  for (int q = 0; q < 4; ++q) bv[q] = *(const float4*)&bias[n0 + 64*q + tx*4];
  #pragma unroll
  for (int i = 0; i < 8; ++i) {
    float* cp = C + (size_t)(m0 + ty*8 + i) * HID + n0 + tx*4;
    #pragma unroll
    for (int q = 0; q < 4; ++q) {
      const float4 v = {acc[i][2*q].x + bv[q].x, acc[i][2*q].y + bv[q].y,
                        acc[i][2*q+1].x + bv[q].z, acc[i][2*q+1].y + bv[q].w};
      *(float4*)(cp + 64*q) = v;
    }
  }
}

// ---------------- LIF scan (bit-identical to np fp32 reference given xp) ----------------
__device__ __forceinline__ float lif_step(float y, float v[4], float av[4]) {
  float as3 = 0.f;
  #pragma unroll
  for (int l = 0; l < 4; ++l) {
    float vv = v[l];
    float accv = 0.f, accs = 0.f;
    #pragma unroll
    for (int k = 0; k < 4; ++k) {
      const float d = y - vv;                        // round(inp - v)
      vv = __builtin_fmaf(d, 0.5f, vv);              // round(v + d*0.5): d*0.5 exact
      const float spk = (vv >= 1.0f) ? 1.0f : 0.0f;  // v-1>=0 <=> v>=1 (exact)
      vv -= spk;                                     // soft reset
      accv += vv;
      accs += spk;
    }
    v[l] = vv;
    const float a = accv * 0.25f;                    // exact /4
    av[l] = a;
    y = a;                                           // next layer consumes avg_v
    as3 = accs;
  }
  return as3;
}

// One thread per neuron. xp loads are INDEPENDENT across t (precomputed array).
// v4: 8-deep prefetch (old 4-deep gave ~1024 issue-cycles of cover vs ~900cy HBM
// latency — marginal; 8-deep doubles the cover) + nontemporal xp loads / out stores
// (both touched exactly once; keep them from thrashing L2/L3 so xp stays L3-resident
// after gemm writes it).
__global__ __launch_bounds__(256) void lif_scan(
    const float* __restrict__ xp, float* __restrict__ outp, float* __restrict__ vstate,
    int tc, int first, int last) {
  const int idx = blockIdx.x * 256 + threadIdx.x;
  float v[4];
  if (first) {
    #pragma unroll
    for (int l = 0; l < 4; ++l) v[l] = 0.f;
  } else {
    #pragma unroll
    for (int l = 0; l < 4; ++l) v[l] = vstate[(size_t)l * BH + idx];
  }
  float av[4] = {0.f, 0.f, 0.f, 0.f};
  const float* p = xp + idx;
  float* op = outp + idx;

  if ((tc & 7) == 0 && tc >= 16) {
    float curb[8];
    #pragma unroll
    for (int i = 0; i < 8; ++i) curb[i] = __builtin_nontemporal_load(&p[(size_t)i * BH]);
    for (int t = 0; t + 8 < tc; t += 8) {
      float nxtb[8];
      #pragma unroll
      for (int i = 0; i < 8; ++i)
        nxtb[i] = __builtin_nontemporal_load(&p[(size_t)(i + 8) * BH]);  // pre-compute
      #pragma unroll
      for (int i = 0; i < 8; ++i) {
        const float as3 = lif_step(curb[i], v, av);
        __builtin_nontemporal_store(as3 * 0.25f, &op[(size_t)i * BH]);
      }
      #pragma unroll
      for (int i = 0; i < 8; ++i) curb[i] = nxtb[i];
      p += 8 * BH; op += 8 * BH;
    }
    #pragma unroll
    for (int i = 0; i < 8; ++i) {    // tail group, already in registers
      const float as3 = lif_step(curb[i], v, av);
      __builtin_nontemporal_store(as3 * 0.25f, &op[(size_t)i * BH]);
    }
  } else {
    for (int t = 0; t < tc; ++t) {
      const float as3 = lif_step(p[0], v, av);
      *op = as3 * 0.25f;
      p += BH; op += BH;
    }
  }

  if (last) {
    #pragma unroll
    for (int l = 0; l < 4; ++l) vstate[(size_t)l * BH + idx] = av[l];
  } else {
    #pragma unroll
    for (int l = 0; l < 4; ++l) vstate[(size_t)l * BH + idx] = v[l];
  }
}

extern "C" void kernel_launch(void* const* d_in, const int* in_sizes, int n_in,
                              void* d_out, int out_size, void* d_ws, size_t ws_size,
                              hipStream_t stream) {
  const float* x = (const float*)d_in[0];   // [128,512,512] fp32
  const float* W = (const float*)d_in[1];   // [512,512] fp32
  const float* b = (const float*)d_in[2];   // [512] fp32
  float* out    = (float*)d_out;            // [128,512,512] avg spikes (fp32)
  float* states = out + (size_t)TT * BH;    // [4,512,512] final avg_v; also chunk-carry v

  int tc = TT;                              // xp chunk: tc MiB of ws
  while (tc > 1 && (size_t)tc * BH * 4ull > ws_size) tc >>= 1;
  float* xp = (float*)d_ws;
  const int nc = TT / tc;

  for (int c = 0; c < nc; ++c) {
    hipLaunchKernelGGL(gemm_f32, dim3(HID / 256, tc * BSZ / 128), dim3(256), 0, stream,
                       x + (size_t)c * tc * BH, W, b, xp);
    hipLaunchKernelGGL(lif_scan, dim3(BH / 256), dim3(256), 0, stream,
                       xp, out + (size_t)c * tc * BH, states,
                       tc, c == 0 ? 1 : 0, c == nc - 1 ? 1 : 0);
  }
}